// Round 5
// baseline (560.082 us; speedup 1.0000x reference)
//
#include <hip/hip_runtime.h>
#include <math.h>

// ws layout (float offsets)
// strip records: [2 parity][256 records][1664 floats] — 8B LL-packet format:
//   832 packets x 8B, packet = {float data, u32 tag}; boundary float f (baseline
//   layout below) lives at float offset 2f.
//   HT  f   0..127  rows 0..3   x cols 0..31
//   HB  f 128..255  rows 60..63 x cols 0..31
//   VL  f 256..511  rows 0..63  x cols 0..3
//   VR  f 512..767  rows 0..63  x cols 28..31
//   CTL f 768..783  CTR 784..799  CBL 800..815  CBR 816..831
// 8B is the single-copy-atomicity grain on gfx9xx (16B packets tore in r3).
#define SB_OFF   0
#define REC      1664
#define PAR      425984      // 256 * 1664
#define E_OFF    851968      // e [128][2048] = 262144 floats ; total ~4.25 MB

typedef float vf4 __attribute__((ext_vector_type(4)));
typedef float vf2 __attribute__((ext_vector_type(2)));

__device__ __forceinline__ float fast_tanh(float x) {
  x = fminf(fmaxf(x, -15.f), 15.f);
  float ex = __expf(2.f * x);
  return __fdividef(ex - 1.f, ex + 1.f);
}

template <int CTRL>
__device__ __forceinline__ float dpp_add(float v) {
  int x = __builtin_amdgcn_update_dpp(0, __float_as_int(v), CTRL, 0xF, 0xF, true);
  return v + __int_as_float(x);
}

// LL packet: 8B single-transaction store {data, tag}, LLC-scope (sc0 sc1).
// Naturally-aligned 64-bit accesses are single-copy atomic (LLVM AMDGPU memory
// model; RCCL LL precedent) -> embedded tag validates the data in the SAME
// packet. No producer drain, no separate tag store; consumer needs ONE RT.
__device__ __forceinline__ void st_pkt(float* p, float d, unsigned tag) {
  vf2 v; v.x = d; v.y = __uint_as_float(tag);
  asm volatile("global_store_dwordx2 %0, %1, off sc0 sc1" :: "v"(p), "v"(v) : "memory");
}
// Poll TWO adjacent packets (8B apart); both loads fly together -> ~1 RT/try.
// NOTE gfx950 asm modifier order: offset: immediate BEFORE cache flags.
__device__ __forceinline__ void poll2(const float* p, unsigned want, float* d0, float* d1) {
  vf2 a, b; int spins = 0;
  for (;;) {
    asm volatile("global_load_dwordx2 %0, %2, off sc0 sc1\n"
                 "global_load_dwordx2 %1, %2, off offset:8 sc0 sc1\n"
                 "s_waitcnt vmcnt(0)"
                 : "=&v"(a), "=&v"(b) : "v"(p) : "memory");
    if (__float_as_uint(a.y) == want && __float_as_uint(b.y) == want) break;
    __builtin_amdgcn_s_sleep(1);
    if (++spins > (1 << 18)) break;  // fail loud (wrong), never hang
  }
  *d0 = a.x; *d1 = b.x;
}

// ---------------- K0: embed e = (X@W^T)*mask_coarse ; out = bias
// 256 blocks x 256 thr; block = 8 o-rows x 128 t, k-chunked LDS tiling.
// X staged COALESCED. (r14-verified)
__global__ __launch_bounds__(256) void prep_kernel(
    const float* __restrict__ X, const float* __restrict__ W_embed,
    const float* __restrict__ mask_coarse, const float* __restrict__ b_out,
    float* __restrict__ ws, float* __restrict__ out)
{
  __shared__ float Xl[128][36];   // 128 t x 32 k chunk (pad 36)
  __shared__ float Wl[8][36];     // 8 o x 32 k chunk

  const int tid = threadIdx.x, bid = blockIdx.x;  // grid = 256
  float* eb = ws + E_OFF;

  // zero the embedded tag slot of every packet in this block's record (both
  // parities): removes first-run / prior-launch garbage-tag hazard.
  for (int f = tid; f < 832; f += 256) {
    ws[SB_OFF + (size_t)bid * REC + 2 * f + 1]       = 0.f;
    ws[SB_OFF + PAR + (size_t)bid * REC + 2 * f + 1] = 0.f;
  }

  // out = bias (scan_kernel atomicAdds channel contributions on top)
  {
    int idx = bid * 512 + tid * 2;                // 131072 = out_size
    out[idx]     = b_out[(idx >> 6) & 15];
    out[idx + 1] = b_out[((idx + 1) >> 6) & 15];
  }

  const int o0 = bid * 8;
  const int ol = tid & 7;          // o-local 0..7
  const int tg = tid >> 3;         // t-group 0..31 (4 t each)
  float acc[4] = {0.f, 0.f, 0.f, 0.f};

  for (int k0 = 0; k0 < 512; k0 += 32) {
    __syncthreads();  // protect Xl/Wl against reuse from previous chunk
#pragma unroll
    for (int p = 0; p < 4; ++p) {
      int tr = p * 32 + (tid >> 3);
      int kc = (tid & 7) * 4;
      *(float4*)&Xl[tr][kc] = *(const float4*)&X[(size_t)tr * 512 + k0 + kc];
    }
    if (tid < 64) {
      int wr = tid >> 3, wc = (tid & 7) * 4;
      *(float4*)&Wl[wr][wc] = *(const float4*)&W_embed[(size_t)(o0 + wr) * 512 + k0 + wc];
    }
    __syncthreads();
#pragma unroll
    for (int kk = 0; kk < 8; ++kk) {
      float4 w4 = *(const float4*)&Wl[ol][kk * 4];
#pragma unroll
      for (int i = 0; i < 4; ++i) {
        float4 x4 = *(const float4*)&Xl[tg * 4 + i][kk * 4];
        acc[i] = fmaf(w4.x, x4.x, fmaf(w4.y, x4.y, fmaf(w4.z, x4.z, fmaf(w4.w, x4.w, acc[i]))));
      }
    }
  }
  const int o = o0 + ol;
  float mc = mask_coarse[o & 255];
#pragma unroll
  for (int i = 0; i < 4; ++i)
    eb[(size_t)(tg * 4 + i) * 2048 + o] = acc[i] * mc;
}

// ---------------- K1: persistent scan. 256 blocks x 512 threads.
// 8 ch x (4x8 tiles of 64x32). Double-buffered LDS state, ONE barrier/step.
// Exchange: 8B LL-packet protocol (see header). Baseline r0 schedule otherwise.
__global__ __launch_bounds__(512, 2) void scan_kernel(
    const float* __restrict__ mask_fine, const float* __restrict__ W_deconv,
    const float* __restrict__ w1, const float* __restrict__ w2,
    const float* __restrict__ w_out, float* __restrict__ ws,
    float* __restrict__ out)
{
  __shared__ float zin[2][72 * 44];     // Z parity buffers, tile + 4-halo
  __shared__ float rowbuf[2][64 * 17];  // readout partials, parity

  const int tid  = threadIdx.x;       // 0..511
  const int bid  = blockIdx.x;
  const int ch   = bid >> 5;
  const int tile = bid & 31;
  const int tI = tile >> 3, tJ = tile & 7;
  const int r0 = tI << 6, c0 = tJ << 5;
  const int row = tid >> 3;           // 0..63
  const int cg  = tid & 7;
  const int lc  = cg << 2;

  float* Zb = ws + SB_OFF;
  const float* eb = ws + E_OFF;
  const int myoff = bid * REC;        // (ch*32+tile) == bid

  // ---- per-thread fixed constants
  const int i0 = (r0 + row) >> 4;
  const int jj = (c0 + lc) >> 4;
  float4 wd[8];
#pragma unroll
  for (int c = 0; c < 8; ++c)
    wd[c] = *(const float4*)&W_deconv[(((c * 8 + ch) * 16) + (row & 15)) * 16 + (lc & 15)];
  float4 mf = *(const float4*)&mask_fine[(size_t)(r0 + row) * 256 + c0 + lc];
  float4 wo[16];
#pragma unroll
  for (int oc = 0; oc < 16; ++oc)
    wo[oc] = *(const float4*)&w_out[(((oc * 8 + ch) * 32) + (row & 31)) * 32 + lc];
  float w1s[9], w2s[25];
#pragma unroll
  for (int k = 0; k < 9; ++k)
    w1s[k] = __uint_as_float(__builtin_amdgcn_readfirstlane(__float_as_uint(w1[ch * 9 + k])));
#pragma unroll
  for (int k = 0; k < 25; ++k)
    w2s[k] = __uint_as_float(__builtin_amdgcn_readfirstlane(__float_as_uint(w2[ch * 25 + k])));

  // ---- fixed halo-read assignment: 416 consumers; each owns 2 packets
  // (mapping re-verified against the r0 baseline, float-for-float)
  int rd_src = 0, rd_dst = 0;
  const bool hasrd = (tid < 416);
  if (hasrd) {
    int u = tid, di = 0, dj = 0, chunk = 0, dst = 0;
    if (u < 64) {              // top rows 0..3 <- U.HB (pairs 64..127)
      di = -1; chunk = 64 + u;
      int r = u >> 4, c = (u * 2) & 31;
      dst = r * 44 + 4 + c;
    } else if (u < 128) {      // bottom rows 68..71 <- D.HT (pairs 0..63)
      int v = u - 64; di = 1; chunk = v;
      int r = v >> 4, c = (v * 2) & 31;
      dst = (68 + r) * 44 + 4 + c;
    } else if (u < 256) {      // left cols 0..3, rows 4..67 <- L.VR (pairs 256..383)
      int v = u - 128; dj = -1; chunk = 256 + v;
      int r = v >> 1, c = (v & 1) * 2;
      dst = (4 + r) * 44 + c;
    } else if (u < 384) {      // right cols 36..39, rows 4..67 <- R.VL (pairs 128..255)
      int v = u - 256; dj = 1; chunk = 128 + v;
      int r = v >> 1, c = (v & 1) * 2;
      dst = (4 + r) * 44 + 36 + c;
    } else {                   // corners, 8 pairs each
      int v = u - 384, cc = v >> 3, k = v & 7;
      int r = k >> 1, c2 = (k & 1) * 2;
      if (cc == 0)      { di = -1; dj = -1; chunk = 408 + k; dst = r * 44 + c2; }            // TL <- CBR
      else if (cc == 1) { di = -1; dj = 1;  chunk = 400 + k; dst = r * 44 + 36 + c2; }       // TR <- CBL
      else if (cc == 2) { di = 1;  dj = -1; chunk = 392 + k; dst = (68 + r) * 44 + c2; }     // BL <- CTR
      else              { di = 1;  dj = 1;  chunk = 384 + k; dst = (68 + r) * 44 + 36 + c2; }// BR <- CTL
    }
    int nI = (tI + di) & 3, nJ = (tJ + dj) & 7;
    rd_src = (ch * 32 + nI * 8 + nJ) * REC + chunk * 4;  // pair -> 2 packets (4 floats)
    rd_dst = dst;
  }

  // init both parity buffers (Z0 = 0, incl. halo)
  for (int k = tid; k < 2 * 72 * 44; k += 512) zin[0][k] = 0.f;
  __syncthreads();

  for (int t = 0; t < 128; ++t) {
    float* sb = Zb + (size_t)((t + 1) & 1) * PAR;      // records for Z_{t+1}
    const float* zr = zin[t & 1];
    float*       zw = zin[(t + 1) & 1];
    float*       rb = rowbuf[t & 1];

    // input-path e values (read-only, L2-resident)
    float ev[8];
#pragma unroll
    for (int c = 0; c < 8; ++c)
      ev[c] = eb[(size_t)t * 2048 + c * 256 + i0 * 16 + jj];

    // ---- compute Z_{t+1} for this thread's 4 px (reads zr = Z_t incl halo)
    float c1a[4] = {0, 0, 0, 0}, c2a[4] = {0, 0, 0, 0};
    {
      float w[12];
      auto load_row = [&](int zrr) {
        float4 A  = *(const float4*)&zr[zrr * 44 + lc];
        float4 B  = *(const float4*)&zr[zrr * 44 + lc + 4];
        float4 Cq = *(const float4*)&zr[zrr * 44 + lc + 8];
        w[0]=A.x; w[1]=A.y; w[2]=A.z; w[3]=A.w;
        w[4]=B.x; w[5]=B.y; w[6]=B.z; w[7]=B.w;
        w[8]=Cq.x; w[9]=Cq.y; w[10]=Cq.z; w[11]=Cq.w;
      };
      auto k2row = [&](int a) {
#pragma unroll
        for (int j = 0; j < 4; ++j)
#pragma unroll
          for (int b = 0; b < 5; ++b)
            c2a[j] = fmaf(w[j + 2 * b], w2s[a * 5 + b], c2a[j]);
      };
      auto k1row = [&](int a) {
#pragma unroll
        for (int j = 0; j < 4; ++j)
#pragma unroll
          for (int b = 0; b < 3; ++b)
            c1a[j] = fmaf(w[j + 3 + b], w1s[a * 3 + b], c1a[j]);
      };
      load_row(row + 0); k2row(0);
      load_row(row + 2); k2row(1);
      load_row(row + 3); k1row(0);
      load_row(row + 4); k1row(1); k2row(2);
      load_row(row + 5); k1row(2);
      load_row(row + 6); k2row(3);
      load_row(row + 8); k2row(4);
    }
    float zv[4];
    {
      const float* mfp = (const float*)&mf;
#pragma unroll
      for (int j = 0; j < 4; ++j) {
        float u = 0.f;
#pragma unroll
        for (int c = 0; c < 8; ++c)
          u = fmaf(ev[c], ((const float*)&wd[c])[j], u);
        float val = fmaf(0.9f, c1a[j], fmaf(0.1f, c2a[j], mfp[j] * u));
        zv[j] = fast_tanh(val);
      }
    }

    // ---- publish self-validating 8B LL packets (fire-and-forget, no drain)
    // boundary float f -> packet at float offset 2f; same f-layout as baseline.
    if (t < 127) {
      float* rec = sb + myoff;
      const unsigned tg = (unsigned)(t + 1);
      if (row < 4) {                                   // HT: f0 = row*32+lc
        float* p = rec + 2 * (row * 32 + lc);
#pragma unroll
        for (int j = 0; j < 4; ++j) st_pkt(p + 2 * j, zv[j], tg);
      }
      if (row >= 60) {                                 // HB: f0 = 128+(row-60)*32+lc
        float* p = rec + 2 * (128 + (row - 60) * 32 + lc);
#pragma unroll
        for (int j = 0; j < 4; ++j) st_pkt(p + 2 * j, zv[j], tg);
      }
      if (lc == 0) {                                   // VL: f0 = 256+row*4
        float* p = rec + 2 * (256 + row * 4);
#pragma unroll
        for (int j = 0; j < 4; ++j) st_pkt(p + 2 * j, zv[j], tg);
      }
      if (lc == 28) {                                  // VR: f0 = 512+row*4
        float* p = rec + 2 * (512 + row * 4);
#pragma unroll
        for (int j = 0; j < 4; ++j) st_pkt(p + 2 * j, zv[j], tg);
      }
      if (row < 4 && lc == 0) {                        // CTL: f0 = 768+row*4
        float* p = rec + 2 * (768 + row * 4);
#pragma unroll
        for (int j = 0; j < 4; ++j) st_pkt(p + 2 * j, zv[j], tg);
      }
      if (row < 4 && lc == 28) {                       // CTR: f0 = 784+row*4
        float* p = rec + 2 * (784 + row * 4);
#pragma unroll
        for (int j = 0; j < 4; ++j) st_pkt(p + 2 * j, zv[j], tg);
      }
      if (row >= 60 && lc == 0) {                      // CBL: f0 = 800+(row-60)*4
        float* p = rec + 2 * (800 + (row - 60) * 4);
#pragma unroll
        for (int j = 0; j < 4; ++j) st_pkt(p + 2 * j, zv[j], tg);
      }
      if (row >= 60 && lc == 28) {                     // CBR: f0 = 816+(row-60)*4
        float* p = rec + 2 * (816 + (row - 60) * 4);
#pragma unroll
        for (int j = 0; j < 4; ++j) st_pkt(p + 2 * j, zv[j], tg);
      }
    }

    // ---- commit interior into the OTHER parity buffer
    *(float4*)&zw[(4 + row) * 44 + 4 + lc] = make_float4(zv[0], zv[1], zv[2], zv[3]);

    // ---- readout FMAs + octet DPP reduce -> rowbuf[parity]
    float racc[16];
#pragma unroll
    for (int oc = 0; oc < 16; ++oc) {
      const float* wop = (const float*)&wo[oc];
      racc[oc] = fmaf(zv[0], wop[0], fmaf(zv[1], wop[1], fmaf(zv[2], wop[2], zv[3] * wop[3])));
    }
#pragma unroll
    for (int k = 0; k < 16; ++k) {
      racc[k] = dpp_add<0xB1>(racc[k]);
      racc[k] = dpp_add<0x4E>(racc[k]);
      racc[k] = dpp_add<0x141>(racc[k]);
    }
    rb[row * 17 + (cg << 1)]     = racc[cg << 1];
    rb[row * 17 + (cg << 1) + 1] = racc[(cg << 1) + 1];

    // ---- halo: poll the two owned packets (tags embedded; ONE round-trip)
    if (t < 127 && hasrd) {
      float d0, d1;
      poll2(sb + rd_src, (unsigned)(t + 1), &d0, &d1);
      zw[rd_dst]     = d0;
      zw[rd_dst + 1] = d1;
    }

    __syncthreads();  // the ONE barrier: zw (interior+halo) + rowbuf complete

    // ---- stage 2: fold rowbuf[parity] -> atomicAdd out (bias pre-initialized)
    if (tid < 32) {
      int p = tid >> 4, oc = tid & 15;
      float s = 0.f;
#pragma unroll
      for (int r = 0; r < 32; ++r) s += rb[(p * 32 + r) * 17 + oc];
      atomicAdd(&out[t * 1024 + oc * 64 + (2 * tI + p) * 8 + tJ], s);
    }
  }
}

extern "C" void kernel_launch(void* const* d_in, const int* in_sizes, int n_in,
                              void* d_out, int out_size, void* d_ws, size_t ws_size,
                              hipStream_t stream) {
  const float* X           = (const float*)d_in[0];
  const float* W_embed     = (const float*)d_in[1];
  const float* mask_coarse = (const float*)d_in[2];
  const float* mask_fine   = (const float*)d_in[3];
  const float* W_deconv    = (const float*)d_in[4];
  const float* w1          = (const float*)d_in[5];
  const float* w2          = (const float*)d_in[6];
  const float* w_out       = (const float*)d_in[7];
  const float* b_out       = (const float*)d_in[8];
  float* ws  = (float*)d_ws;
  float* out = (float*)d_out;

  prep_kernel<<<dim3(256), dim3(256), 0, stream>>>(X, W_embed, mask_coarse, b_out, ws, out);
  scan_kernel<<<dim3(256), dim3(512), 0, stream>>>(mask_fine, W_deconv, w1, w2, w_out, ws, out);
}